// Round 1
// baseline (205.604 us; speedup 1.0000x reference)
//
#include <hip/hip_runtime.h>
#include <stdint.h>

// ---------------------------------------------------------------------------
// RLMALinear: out = x @ (alpha*R + U@V)^T + bias
//   x: [32,4096,512] f32, U: [512,64] f32, V: [64,512] f32, bias: [512] f32
//   R: jax.random.normal(key(1234^k_iter), (512,512)) / sqrt(512)
// Stage 1: build W in bf16 into d_ws (threefry2x32 counter-mode + erfinv).
// Stage 2: bf16 MFMA GEMM, fp32 accumulate, fp32 out.
// ---------------------------------------------------------------------------

#define M_TOTAL 131072
#define N_DIM 512
#define K_DIM 512
#define RANK 64

typedef __attribute__((ext_vector_type(8))) short bf16x8;
typedef __attribute__((ext_vector_type(4))) float f32x4;

// ---- JAX threefry2x32 (20 rounds, key-schedule inject every 4) ------------
__device__ __forceinline__ void threefry2x32(uint32_t k0, uint32_t k1,
                                             uint32_t x0, uint32_t x1,
                                             uint32_t& y0, uint32_t& y1) {
  uint32_t ks0 = k0, ks1 = k1, ks2 = k0 ^ k1 ^ 0x1BD11BDAu;
  const uint32_t ks[3] = {ks0, ks1, ks2};
  const int R0[4] = {13, 15, 26, 6};
  const int R1[4] = {17, 29, 16, 24};
  x0 += ks[0];
  x1 += ks[1];
#pragma unroll
  for (int g = 0; g < 5; ++g) {
    const int* r = (g & 1) ? R1 : R0;
#pragma unroll
    for (int i = 0; i < 4; ++i) {
      x0 += x1;
      x1 = (x1 << r[i]) | (x1 >> (32 - r[i]));
      x1 ^= x0;
    }
    x0 += ks[(g + 1) % 3];
    x1 += ks[(g + 2) % 3] + (uint32_t)(g + 1);
  }
  y0 = x0;
  y1 = x1;
}

// ---- XLA ErfInv32 (Giles 2012 single-precision polynomial) ----------------
__device__ __forceinline__ float erfinv_f32(float x) {
  float w = -log1pf(-x * x);
  float p;
  if (w < 5.0f) {
    w = w - 2.5f;
    p = 2.81022636e-08f;
    p = fmaf(p, w, 3.43273939e-07f);
    p = fmaf(p, w, -3.5233877e-06f);
    p = fmaf(p, w, -4.39150654e-06f);
    p = fmaf(p, w, 0.00021858087f);
    p = fmaf(p, w, -0.00125372503f);
    p = fmaf(p, w, -0.00417768164f);
    p = fmaf(p, w, 0.246640727f);
    p = fmaf(p, w, 1.50140941f);
  } else {
    w = sqrtf(w) - 3.0f;
    p = -0.000200214257f;
    p = fmaf(p, w, 0.000100950558f);
    p = fmaf(p, w, 0.00134934322f);
    p = fmaf(p, w, -0.00367342844f);
    p = fmaf(p, w, 0.00573950773f);
    p = fmaf(p, w, -0.0076224613f);
    p = fmaf(p, w, 0.00943887047f);
    p = fmaf(p, w, 1.00167406f);
    p = fmaf(p, w, 2.83297682f);
  }
  return p * x;
}

__device__ __forceinline__ unsigned short f32_to_bf16_rtne(float f) {
  uint32_t x = __float_as_uint(f);
  uint32_t r = (x + 0x7FFFu + ((x >> 16) & 1u)) >> 16;
  return (unsigned short)r;
}

// ---- Stage 1: W[o][i] = alpha * R[o][i] + dot(U[o,:], V[:,i]) -> bf16 -----
__global__ __launch_bounds__(256) void build_w_kernel(
    const float* __restrict__ alpha_p, const float* __restrict__ U,
    const float* __restrict__ V, const int* __restrict__ k_iter_p,
    unsigned short* __restrict__ Wb) {
  int idx = blockIdx.x * blockDim.x + threadIdx.x;  // 0 .. 512*512-1
  uint32_t s = (1234u ^ (uint32_t)(*k_iter_p));
  // jax threefry_partitionable counter mode: bits[i] = y0 ^ y1 of
  // threefry2x32(key=(0, s), counter=(hi=0, lo=i))
  uint32_t y0, y1;
  threefry2x32(0u, s, 0u, (uint32_t)idx, y0, y1);
  uint32_t bits = y0 ^ y1;
  // uniform in [-1+2^-24, 1)
  float u01 = __uint_as_float((bits >> 9) | 0x3f800000u) - 1.0f;
  const float lo = -0.99999994f;  // nextafter(-1, 0)
  float u = fmaxf(lo, u01 * 2.0f + lo);
  float rnorm = 1.41421354f * erfinv_f32(u);
  const float scale = 0.044194173824159216f;  // fp32(1/sqrt(512))

  int o = idx >> 9;
  int i = idx & 511;
  float uv = 0.0f;
#pragma unroll 8
  for (int r = 0; r < RANK; ++r)
    uv = fmaf(U[o * RANK + r], V[r * N_DIM + i], uv);

  float w = (*alpha_p) * (rnorm * scale) + uv;
  Wb[idx] = f32_to_bf16_rtne(w);
}

// ---- Stage 2: GEMM out[m][n] = sum_k x[m][k] * W[n][k] + bias[n] ----------
#define BM 128
#define BN 128
#define BK 64
#define LDK 72  // +8 bf16 pad: 144B row stride breaks bank-conflict stride

__global__ __launch_bounds__(256, 2) void gemm_kernel(
    const float* __restrict__ X, const unsigned short* __restrict__ Wb,
    const float* __restrict__ bias, float* __restrict__ Out) {
  __shared__ unsigned short As[BM][LDK];
  __shared__ unsigned short Bs[BN][LDK];

  const int tid = threadIdx.x;
  const int bid = blockIdx.x;
  const int nb = bid & 3;   // n fastest: 4 N-blocks share x panel via L3
  const int mb = bid >> 2;
  const int m0 = mb * BM;
  const int n0 = nb * BN;

  const int lane = tid & 63;
  const int wave = tid >> 6;  // 4 waves, 2x2 -> each owns 64x64
  const int wr = wave >> 1;
  const int wc = wave & 1;

  f32x4 acc[4][4];
#pragma unroll
  for (int i = 0; i < 4; ++i)
#pragma unroll
    for (int j = 0; j < 4; ++j) acc[i][j] = (f32x4){0.f, 0.f, 0.f, 0.f};

  // X staging map: thread t, iter j: row=(t>>4)+j*16, 4 floats at (t&15)*4
  const int xr = tid >> 4;
  const int xc = (tid & 15) * 4;
  // W staging map: thread t, iter j: row=(t>>3)+j*32, 8 bf16 at (t&7)*8
  const int wrow = tid >> 3;
  const int wcol = (tid & 7) * 8;

  for (int kt = 0; kt < K_DIM / BK; ++kt) {
    const int k0 = kt * BK;
    // stage X tile (f32 -> bf16)
#pragma unroll
    for (int j = 0; j < 8; ++j) {
      int row = xr + j * 16;
      float4 v = *reinterpret_cast<const float4*>(
          &X[(size_t)(m0 + row) * K_DIM + k0 + xc]);
      ushort4 pk;
      pk.x = f32_to_bf16_rtne(v.x);
      pk.y = f32_to_bf16_rtne(v.y);
      pk.z = f32_to_bf16_rtne(v.z);
      pk.w = f32_to_bf16_rtne(v.w);
      *reinterpret_cast<ushort4*>(&As[row][xc]) = pk;
    }
    // stage W tile (already bf16)
#pragma unroll
    for (int j = 0; j < 4; ++j) {
      int row = wrow + j * 32;
      bf16x8 v = *reinterpret_cast<const bf16x8*>(
          &Wb[(size_t)(n0 + row) * K_DIM + k0 + wcol]);
      *reinterpret_cast<bf16x8*>(&Bs[row][wcol]) = v;
    }
    __syncthreads();

#pragma unroll
    for (int ks = 0; ks < 2; ++ks) {
      bf16x8 a[4], b[4];
#pragma unroll
      for (int i = 0; i < 4; ++i)
        a[i] = *reinterpret_cast<const bf16x8*>(
            &As[wr * 64 + i * 16 + (lane & 15)][ks * 32 + (lane >> 4) * 8]);
#pragma unroll
      for (int j = 0; j < 4; ++j)
        b[j] = *reinterpret_cast<const bf16x8*>(
            &Bs[wc * 64 + j * 16 + (lane & 15)][ks * 32 + (lane >> 4) * 8]);
#pragma unroll
      for (int i = 0; i < 4; ++i)
#pragma unroll
        for (int j = 0; j < 4; ++j)
          acc[i][j] =
              __builtin_amdgcn_mfma_f32_16x16x32_bf16(a[i], b[j], acc[i][j], 0, 0, 0);
    }
    __syncthreads();
  }

  // epilogue: C mapping col=lane&15, row=(lane>>4)*4+q  [m89/m91 verified]
  const int col = lane & 15;
  const int rbase = (lane >> 4) * 4;
#pragma unroll
  for (int j = 0; j < 4; ++j) {
    int oc = n0 + wc * 64 + j * 16 + col;
    float bv = bias[oc];
#pragma unroll
    for (int i = 0; i < 4; ++i) {
      int orow = m0 + wr * 64 + i * 16 + rbase;
#pragma unroll
      for (int q = 0; q < 4; ++q) {
        Out[(size_t)(orow + q) * N_DIM + oc] = acc[i][j][q] + bv;
      }
    }
  }
}

extern "C" void kernel_launch(void* const* d_in, const int* in_sizes, int n_in,
                              void* d_out, int out_size, void* d_ws,
                              size_t ws_size, hipStream_t stream) {
  (void)in_sizes;
  (void)n_in;
  (void)out_size;
  (void)ws_size;
  const float* x = (const float*)d_in[0];
  const float* alpha = (const float*)d_in[1];
  const float* U = (const float*)d_in[2];
  const float* V = (const float*)d_in[3];
  const float* bias = (const float*)d_in[4];
  const int* k_iter = (const int*)d_in[5];
  float* out = (float*)d_out;
  unsigned short* Wb = (unsigned short*)d_ws;  // 512*512*2 = 512 KiB scratch

  // Stage 1: synthesize W in bf16
  build_w_kernel<<<(N_DIM * K_DIM) / 256, 256, 0, stream>>>(alpha, U, V,
                                                            k_iter, Wb);
  // Stage 2: GEMM
  const int grid = (M_TOTAL / BM) * (N_DIM / BN);  // 1024 * 4 = 4096
  gemm_kernel<<<grid, 256, 0, stream>>>(x, Wb, bias, out);
}

// Round 2
// 165.008 us; speedup vs baseline: 1.2460x; 1.2460x over previous
//
#include <hip/hip_runtime.h>
#include <stdint.h>

// ---------------------------------------------------------------------------
// RLMALinear: out = x @ (alpha*R + U@V)^T + bias
//   x: [32,4096,512] f32, U: [512,64] f32, V: [64,512] f32, bias: [512] f32
//   R: jax.random.normal(key(1234^k_iter), (512,512)) / sqrt(512)
// Stage 1: build W in bf16 into d_ws (threefry2x32 counter-mode + erfinv).
// Stage 2: bf16 MFMA GEMM, fp32 accumulate, fp32 out.
//   R1: XCD-swizzle (x-panel L2 reuse) + reg-prefetch pipeline (T14) +
//       v_cvt_pk_bf16_f32 staging convert.
// ---------------------------------------------------------------------------

#define M_TOTAL 131072
#define N_DIM 512
#define K_DIM 512
#define RANK 64

typedef __attribute__((ext_vector_type(8))) short bf16x8;
typedef __attribute__((ext_vector_type(4))) float f32x4;

// ---- JAX threefry2x32 (20 rounds, key-schedule inject every 4) ------------
__device__ __forceinline__ void threefry2x32(uint32_t k0, uint32_t k1,
                                             uint32_t x0, uint32_t x1,
                                             uint32_t& y0, uint32_t& y1) {
  uint32_t ks2 = k0 ^ k1 ^ 0x1BD11BDAu;
  const uint32_t ks[3] = {k0, k1, ks2};
  const int R0[4] = {13, 15, 26, 6};
  const int R1[4] = {17, 29, 16, 24};
  x0 += ks[0];
  x1 += ks[1];
#pragma unroll
  for (int g = 0; g < 5; ++g) {
    const int* r = (g & 1) ? R1 : R0;
#pragma unroll
    for (int i = 0; i < 4; ++i) {
      x0 += x1;
      x1 = (x1 << r[i]) | (x1 >> (32 - r[i]));
      x1 ^= x0;
    }
    x0 += ks[(g + 1) % 3];
    x1 += ks[(g + 2) % 3] + (uint32_t)(g + 1);
  }
  y0 = x0;
  y1 = x1;
}

// ---- XLA ErfInv32 (Giles 2012 single-precision polynomial) ----------------
__device__ __forceinline__ float erfinv_f32(float x) {
  float w = -log1pf(-x * x);
  float p;
  if (w < 5.0f) {
    w = w - 2.5f;
    p = 2.81022636e-08f;
    p = fmaf(p, w, 3.43273939e-07f);
    p = fmaf(p, w, -3.5233877e-06f);
    p = fmaf(p, w, -4.39150654e-06f);
    p = fmaf(p, w, 0.00021858087f);
    p = fmaf(p, w, -0.00125372503f);
    p = fmaf(p, w, -0.00417768164f);
    p = fmaf(p, w, 0.246640727f);
    p = fmaf(p, w, 1.50140941f);
  } else {
    w = sqrtf(w) - 3.0f;
    p = -0.000200214257f;
    p = fmaf(p, w, 0.000100950558f);
    p = fmaf(p, w, 0.00134934322f);
    p = fmaf(p, w, -0.00367342844f);
    p = fmaf(p, w, 0.00573950773f);
    p = fmaf(p, w, -0.0076224613f);
    p = fmaf(p, w, 0.00943887047f);
    p = fmaf(p, w, 1.00167406f);
    p = fmaf(p, w, 2.83297682f);
  }
  return p * x;
}

__device__ __forceinline__ unsigned short f32_to_bf16_rtne(float f) {
  uint32_t x = __float_as_uint(f);
  uint32_t r = (x + 0x7FFFu + ((x >> 16) & 1u)) >> 16;
  return (unsigned short)r;
}

// ---- Stage 1: W[o][i] = alpha * R[o][i] + dot(U[o,:], V[:,i]) -> bf16 -----
__global__ __launch_bounds__(256) void build_w_kernel(
    const float* __restrict__ alpha_p, const float* __restrict__ U,
    const float* __restrict__ V, const int* __restrict__ k_iter_p,
    unsigned short* __restrict__ Wb) {
  int idx = blockIdx.x * blockDim.x + threadIdx.x;  // 0 .. 512*512-1
  uint32_t s = (1234u ^ (uint32_t)(*k_iter_p));
  uint32_t y0, y1;
  threefry2x32(0u, s, 0u, (uint32_t)idx, y0, y1);
  uint32_t bits = y0 ^ y1;
  float u01 = __uint_as_float((bits >> 9) | 0x3f800000u) - 1.0f;
  const float lo = -0.99999994f;  // nextafter(-1, 0)
  float u = fmaxf(lo, u01 * 2.0f + lo);
  float rnorm = 1.41421354f * erfinv_f32(u);
  const float scale = 0.044194173824159216f;  // fp32(1/sqrt(512))

  int o = idx >> 9;
  int i = idx & 511;
  float uv = 0.0f;
#pragma unroll 8
  for (int r = 0; r < RANK; ++r)
    uv = fmaf(U[o * RANK + r], V[r * N_DIM + i], uv);

  float w = (*alpha_p) * (rnorm * scale) + uv;
  Wb[idx] = f32_to_bf16_rtne(w);
}

// ---- Stage 2: GEMM out[m][n] = sum_k x[m][k] * W[n][k] + bias[n] ----------
#define BM 128
#define BN 128
#define BK 64
#define LDK 72  // +8 bf16 pad: 144B row stride -> 2-way (free) on frag reads
#define NKT (K_DIM / BK)

__global__ __launch_bounds__(256, 3) void gemm_kernel(
    const float* __restrict__ X, const unsigned short* __restrict__ Wb,
    const float* __restrict__ bias, float* __restrict__ Out) {
  __shared__ unsigned short As[BM][LDK];
  __shared__ unsigned short Bs[BN][LDK];

  const int tid = threadIdx.x;
  // XCD-aware bijective swizzle: grid 4096 = 8 XCDs x 512. Each XCD gets an
  // exclusive mb-range; the 4 nb-sharers of one x-panel are adjacent.
  const int p = blockIdx.x;
  const int l = (p & 7) * 512 + (p >> 3);
  const int nb = l & 3;
  const int mb = l >> 2;
  const int m0 = mb * BM;
  const int n0 = nb * BN;

  const int lane = tid & 63;
  const int wave = tid >> 6;  // 4 waves, 2x2 -> each owns 64x64
  const int wr = wave >> 1;
  const int wc = wave & 1;

  f32x4 acc[4][4];
#pragma unroll
  for (int i = 0; i < 4; ++i)
#pragma unroll
    for (int j = 0; j < 4; ++j) acc[i][j] = (f32x4){0.f, 0.f, 0.f, 0.f};

  // X staging map: thread t, iter j: row=(t>>4)+j*16, 4 floats at (t&15)*4
  const int xr = tid >> 4;
  const int xc = (tid & 15) * 4;
  // W staging map: thread t, iter j: row=(t>>3)+j*32, 8 bf16 at (t&7)*8
  const int wrow = tid >> 3;
  const int wcol = (tid & 7) * 8;

  // register prefetch state (all statically indexed -> stays in VGPRs)
  float4 xv[8];
  bf16x8 wv[4];

#define ISSUE_LOADS(kt_)                                                   \
  {                                                                        \
    const int k0_ = (kt_)*BK;                                              \
    _Pragma("unroll") for (int j = 0; j < 8; ++j) xv[j] =                  \
        *reinterpret_cast<const float4*>(                                  \
            &X[(size_t)(m0 + xr + j * 16) * K_DIM + k0_ + xc]);            \
    _Pragma("unroll") for (int j = 0; j < 4; ++j) wv[j] =                  \
        *reinterpret_cast<const bf16x8*>(                                  \
            &Wb[(size_t)(n0 + wrow + j * 32) * K_DIM + k0_ + wcol]);       \
  }

#define WRITE_LDS()                                                        \
  {                                                                        \
    _Pragma("unroll") for (int j = 0; j < 8; ++j) {                        \
      uint32_t p0_, p1_;                                                   \
      asm("v_cvt_pk_bf16_f32 %0, %1, %2"                                   \
          : "=v"(p0_)                                                      \
          : "v"(xv[j].x), "v"(xv[j].y));                                   \
      asm("v_cvt_pk_bf16_f32 %0, %1, %2"                                   \
          : "=v"(p1_)                                                      \
          : "v"(xv[j].z), "v"(xv[j].w));                                   \
      uint2 pk_;                                                           \
      pk_.x = p0_;                                                         \
      pk_.y = p1_;                                                         \
      *reinterpret_cast<uint2*>(&As[xr + j * 16][xc]) = pk_;               \
    }                                                                      \
    _Pragma("unroll") for (int j = 0; j < 4; ++j)                          \
        *reinterpret_cast<bf16x8*>(&Bs[wrow + j * 32][wcol]) = wv[j];      \
  }

  // prologue: stage tile 0
  ISSUE_LOADS(0)
  WRITE_LDS()
  __syncthreads();

  for (int kt = 0; kt < NKT; ++kt) {
    if (kt < NKT - 1) {
      ISSUE_LOADS(kt + 1)
      // keep the global-load issue above the compute phase
      asm volatile("" ::: "memory");
    }

    // compute current tile from LDS
#pragma unroll
    for (int ks = 0; ks < 2; ++ks) {
      bf16x8 a[4], b[4];
#pragma unroll
      for (int i = 0; i < 4; ++i)
        a[i] = *reinterpret_cast<const bf16x8*>(
            &As[wr * 64 + i * 16 + (lane & 15)][ks * 32 + (lane >> 4) * 8]);
#pragma unroll
      for (int j = 0; j < 4; ++j)
        b[j] = *reinterpret_cast<const bf16x8*>(
            &Bs[wc * 64 + j * 16 + (lane & 15)][ks * 32 + (lane >> 4) * 8]);
#pragma unroll
      for (int i = 0; i < 4; ++i)
#pragma unroll
        for (int j = 0; j < 4; ++j)
          acc[i][j] = __builtin_amdgcn_mfma_f32_16x16x32_bf16(a[i], b[j],
                                                              acc[i][j], 0, 0, 0);
    }
    __syncthreads();  // all waves done reading LDS

    if (kt < NKT - 1) {
      WRITE_LDS()  // vmcnt wait auto-inserted before first xv use
      __syncthreads();
    }
  }

  // epilogue: C mapping col=lane&15, row=(lane>>4)*4+q  [m89/m91 verified]
  const int col = lane & 15;
  const int rbase = (lane >> 4) * 4;
#pragma unroll
  for (int j = 0; j < 4; ++j) {
    int oc = n0 + wc * 64 + j * 16 + col;
    float bv = bias[oc];
#pragma unroll
    for (int i = 0; i < 4; ++i) {
      int orow = m0 + wr * 64 + i * 16 + rbase;
#pragma unroll
      for (int q = 0; q < 4; ++q) {
        Out[(size_t)(orow + q) * N_DIM + oc] = acc[i][j][q] + bv;
      }
    }
  }
#undef ISSUE_LOADS
#undef WRITE_LDS
}

extern "C" void kernel_launch(void* const* d_in, const int* in_sizes, int n_in,
                              void* d_out, int out_size, void* d_ws,
                              size_t ws_size, hipStream_t stream) {
  (void)in_sizes;
  (void)n_in;
  (void)out_size;
  (void)ws_size;
  const float* x = (const float*)d_in[0];
  const float* alpha = (const float*)d_in[1];
  const float* U = (const float*)d_in[2];
  const float* V = (const float*)d_in[3];
  const float* bias = (const float*)d_in[4];
  const int* k_iter = (const int*)d_in[5];
  float* out = (float*)d_out;
  unsigned short* Wb = (unsigned short*)d_ws;  // 512*512*2 = 512 KiB scratch

  build_w_kernel<<<(N_DIM * K_DIM) / 256, 256, 0, stream>>>(alpha, U, V,
                                                            k_iter, Wb);
  const int grid = (M_TOTAL / BM) * (N_DIM / BN);  // 1024 * 4 = 4096
  gemm_kernel<<<grid, 256, 0, stream>>>(x, Wb, bias, out);
}